// Round 16
// baseline (94.166 us; speedup 1.0000x reference)
//
#include <hip/hip_runtime.h>
#include <math.h>

#define BATCH 4096
#define DIM 128
#define LU 10
#define LI 20
#define NS 12288   // 3 * BATCH samples

typedef float  f32x4  __attribute__((ext_vector_type(4)));
typedef short  s16x8  __attribute__((ext_vector_type(8)));

// round-to-nearest-even fp32 -> bf16
__device__ __forceinline__ short f2bf(float x) {
    unsigned u = __float_as_uint(x);
    u += 0x7FFFu + ((u >> 16) & 1u);
    return (short)(u >> 16);
}

// ---------------------------------------------------------------------------
// K_prep: weight transposes -> bf16; ef tables -> bf16; proj tables; PLUS
// entity scores sE (8-lane-group dots).
//   [0,704)       weight transposes
//   [704,1329)    ef16
//   [1329,1579)   efU16
//   [1579,2204)   projIP/projII
//   [2204,2454)   projUP/projUI
//   [2454,2838)   sEP/sEI entity scores (8 samples per wave)
// ---------------------------------------------------------------------------
__global__ __launch_bounds__(256) void k_prep(
    const float* __restrict__ enc_W, const float* __restrict__ dec_W,
    const float* __restrict__ fc11_W, const float* __restrict__ fc12_W,
    const float* __restrict__ W_pop, const float* __restrict__ W_int,
    const float* __restrict__ ef_item, const float* __restrict__ ef_user,
    const float* __restrict__ pop_i, const float* __restrict__ int_i,
    const float* __restrict__ pop_u, const float* __restrict__ int_u,
    const int* __restrict__ user_idx, const int* __restrict__ pos_idx,
    const int* __restrict__ neg_idx,
    const float* __restrict__ emb_user, const float* __restrict__ emb_item,
    short* __restrict__ encWT, short* __restrict__ decWT,
    short* __restrict__ fc11WT, short* __restrict__ fc12WT,
    short* __restrict__ wpopT, short* __restrict__ wintT,
    short* __restrict__ ef16, short* __restrict__ efU16,
    float* __restrict__ projIP, float* __restrict__ projII,
    float* __restrict__ projUP, float* __restrict__ projUI,
    float* __restrict__ sEP, float* __restrict__ sEI)
{
    __shared__ float tile[32][33];
    const int b = blockIdx.x;
    const int t = threadIdx.x;

    if (b < 704) {
        const float* src; short* dst; int r0, c0, src_ld, dst_ld;
        if (b < 320) {
            int tk = b % 80, tj = b / 80;
            src = enc_W; dst = encWT; r0 = tk * 32; c0 = tj * 32; src_ld = 128; dst_ld = 2560;
        } else if (b < 640) {
            int tb = b - 320; int tc = tb % 80, td = tb / 80;
            src = dec_W; dst = decWT; r0 = td * 32; c0 = tc * 32; src_ld = 2560; dst_ld = 128;
        } else if (b < 656) {
            int tb = b - 640; int tk = tb % 4, tj = tb / 4;
            src = fc11_W; dst = fc11WT; r0 = tk * 32; c0 = tj * 32; src_ld = 128; dst_ld = 128;
        } else if (b < 672) {
            int tb = b - 656; int tk = tb % 4, tj = tb / 4;
            src = fc12_W; dst = fc12WT; r0 = tk * 32; c0 = tj * 32; src_ld = 128; dst_ld = 128;
        } else if (b < 688) {
            int tb = b - 672; int tk = tb % 4, tj = tb / 4;
            src = W_pop; dst = wpopT; r0 = tk * 32; c0 = tj * 32; src_ld = 128; dst_ld = 128;
        } else {
            int tb = b - 688; int tk = tb % 4, tj = tb / 4;
            src = W_int; dst = wintT; r0 = tk * 32; c0 = tj * 32; src_ld = 128; dst_ld = 128;
        }
        for (int q = 0; q < 4; ++q) {
            int e = t + q * 256;
            int r = e >> 5, c = e & 31;
            tile[r][c] = src[(size_t)(r0 + r) * src_ld + (c0 + c)];
        }
        __syncthreads();
        for (int q = 0; q < 4; ++q) {
            int e = t + q * 256;
            int r = e >> 5, c = e & 31;
            dst[(size_t)(c0 + r) * dst_ld + (r0 + c)] = f2bf(tile[c][r]);
        }
    } else if (b < 1329) {
        int base = (b - 704) * 1024 + t * 4;
        float4 v = *(const float4*)(ef_item + base);
        short4 o;
        o.x = f2bf(v.x); o.y = f2bf(v.y); o.z = f2bf(v.z); o.w = f2bf(v.w);
        *(short4*)(ef16 + base) = o;
    } else if (b < 1579) {
        int base = (b - 1329) * 1024 + t * 4;
        float4 v = *(const float4*)(ef_user + base);
        short4 o;
        o.x = f2bf(v.x); o.y = f2bf(v.y); o.z = f2bf(v.z); o.w = f2bf(v.w);
        *(short4*)(efU16 + base) = o;
    } else if (b < 2454) {
        const int pb = b - 1579;
        const float* tab; const float* v0p; const float* v1p;
        float* o0; float* o1; int row;
        if (pb < 625) {
            row = pb * 8 + (t >> 5);
            tab = ef_item; v0p = pop_i; v1p = int_i; o0 = projIP; o1 = projII;
        } else {
            row = (pb - 625) * 8 + (t >> 5);
            tab = ef_user; v0p = pop_u; v1p = int_u; o0 = projUP; o1 = projUI;
        }
        const int d = (t & 31) * 4;
        float4 rv = *(const float4*)(tab + (size_t)row * DIM + d);
        float4 a  = *(const float4*)(v0p + d);
        float4 c  = *(const float4*)(v1p + d);
        float s0 = rv.x * a.x + rv.y * a.y + rv.z * a.z + rv.w * a.w;
        float s1 = rv.x * c.x + rv.y * c.y + rv.z * c.z + rv.w * c.w;
        s0 += __shfl_xor(s0, 1, 64);  s1 += __shfl_xor(s1, 1, 64);
        s0 += __shfl_xor(s0, 2, 64);  s1 += __shfl_xor(s1, 2, 64);
        s0 += __shfl_xor(s0, 4, 64);  s1 += __shfl_xor(s1, 4, 64);
        s0 += __shfl_xor(s0, 8, 64);  s1 += __shfl_xor(s1, 8, 64);
        s0 += __shfl_xor(s0, 16, 64); s1 += __shfl_xor(s1, 16, 64);
        if ((t & 31) == 0) { o0[row] = s0; o1[row] = s1; }
    } else {
        // entity scores: 8-lane group per sample, 8 samples per wave
        const int pb   = b - 2454;               // [0,384)
        const int wv   = pb * 4 + (t >> 6);      // global wave [0,1536)
        const int lane = t & 63;
        const int g    = lane >> 3;              // sample slot [0,8)
        const int c    = lane & 7;               // 16-dim chunk
        const int s    = wv * 8 + g;             // [0,12288)
        const int br   = s >> 12;
        const int i    = s & 4095;
        const int* idxp   = (br == 0) ? user_idx : (br == 1 ? pos_idx : neg_idx);
        const float* etab = (br == 0) ? emb_user : emb_item;
        const float* vp   = (br == 0) ? pop_u : pop_i;
        const float* vi   = (br == 0) ? int_u : int_i;
        const int idx = idxp[i];
        const float* rowp = etab + (size_t)idx * DIM + c * 16;
        float sp = 0.f, si = 0.f;
#pragma unroll
        for (int j = 0; j < 4; ++j) {
            float4 rv = *(const float4*)(rowp + j * 4);
            float4 va = *(const float4*)(vp + c * 16 + j * 4);
            float4 vb = *(const float4*)(vi + c * 16 + j * 4);
            sp += rv.x * va.x + rv.y * va.y + rv.z * va.z + rv.w * va.w;
            si += rv.x * vb.x + rv.y * vb.y + rv.z * vb.z + rv.w * vb.w;
        }
        sp += __shfl_xor(sp, 1, 64); si += __shfl_xor(si, 1, 64);
        sp += __shfl_xor(sp, 2, 64); si += __shfl_xor(si, 2, 64);
        sp += __shfl_xor(sp, 4, 64); si += __shfl_xor(si, 4, 64);
        if (c == 0) { sEP[s] = sp; sEI[s] = si; }
    }
}

// ---------------------------------------------------------------------------
// k_W: softmax weights per sample, thread-per-sample (48 blocks x 256).
// Stores UNNORMALIZED weights wl[vec][l][s] (coalesced over s) + rinv[s].
// ---------------------------------------------------------------------------
template<int L>
__device__ __forceinline__ void w_one(
    int s, int i, const int* __restrict__ featp,
    const float* __restrict__ projP, const float* __restrict__ projI,
    const float* __restrict__ sEP, const float* __restrict__ sEI,
    float* __restrict__ wlP, float* __restrict__ wlI,
    float* __restrict__ rinvH, float* __restrict__ rinvC)
{
    const float s0p = sEP[s], s0i = sEI[s];
    float mh = s0p, mc = s0i;
#pragma unroll
    for (int l = 0; l < L; ++l) {
        int f = featp[i * L + l];
        if (f != 0) {
            mh = fmaxf(mh, projP[f]);
            mc = fmaxf(mc, projI[f]);
        }
    }
    float sh = __expf(s0p - mh), sc = __expf(s0i - mc);
    wlP[s] = sh;   // l = 0 (entity)
    wlI[s] = sc;
#pragma unroll
    for (int l = 0; l < L; ++l) {
        int f = featp[i * L + l];
        float eh = 0.f, ec = 0.f;
        if (f != 0) {
            eh = __expf(projP[f] - mh);
            ec = __expf(projI[f] - mc);
        }
        wlP[(l + 1) * NS + s] = eh;
        wlI[(l + 1) * NS + s] = ec;
        sh += eh; sc += ec;
    }
    rinvH[s] = 1.f / sh;
    rinvC[s] = 1.f / sc;
}

__global__ __launch_bounds__(256) void k_W(
    const int* __restrict__ user_feat, const int* __restrict__ pos_feat,
    const int* __restrict__ neg_feat,
    const float* __restrict__ projIP, const float* __restrict__ projII,
    const float* __restrict__ projUP, const float* __restrict__ projUI,
    const float* __restrict__ sEP, const float* __restrict__ sEI,
    float* __restrict__ wlP, float* __restrict__ wlI,
    float* __restrict__ rinvH, float* __restrict__ rinvC)
{
    const int s = blockIdx.x * 256 + threadIdx.x;   // [0, NS)
    const int i = s & 4095;
    if (s < 4096) {
        w_one<LU>(s, i, user_feat, projUP, projUI, sEP, sEI, wlP, wlI, rinvH, rinvC);
    } else if (s < 8192) {
        w_one<LI>(s, i, pos_feat, projIP, projII, sEP, sEI, wlP, wlI, rinvH, rinvC);
    } else {
        w_one<LI>(s, i, neg_feat, projIP, projII, sEP, sEI, wlP, wlI, rinvH, rinvC);
    }
}

// ---------------------------------------------------------------------------
// pool_p<L>: weighted-sum only. 4 samples per wave, 16 lanes/sample,
// 8 dims/lane. All loads independent; no exp, no shfl.
// ---------------------------------------------------------------------------
template<int L>
__device__ __forceinline__ void pool_p(
    const int* __restrict__ idxp, const int* __restrict__ featp,
    const float* __restrict__ etab, const unsigned short* __restrict__ ftab16,
    const float* __restrict__ wlP, const float* __restrict__ wlI,
    const float* __restrict__ rinvH, const float* __restrict__ rinvC,
    float* __restrict__ poolH, float* __restrict__ poolC,
    int i, int sg, int c)
{
    const int d0 = c * 8;

    float p0=0,p1=0,p2=0,p3=0,p4=0,p5=0,p6=0,p7=0;
    float q0=0,q1=0,q2=0,q3=0,q4=0,q5=0,q6=0,q7=0;

    // entity row (fp32)
    {
        const float* er = etab + (size_t)idxp[i] * DIM + d0;
        float4 ea = *(const float4*)er;
        float4 eb = *(const float4*)(er + 4);
        float wp = wlP[sg], wi = wlI[sg];
        p0 += wp*ea.x; p1 += wp*ea.y; p2 += wp*ea.z; p3 += wp*ea.w;
        p4 += wp*eb.x; p5 += wp*eb.y; p6 += wp*eb.z; p7 += wp*eb.w;
        q0 += wi*ea.x; q1 += wi*ea.y; q2 += wi*ea.z; q3 += wi*ea.w;
        q4 += wi*eb.x; q5 += wi*eb.y; q6 += wi*eb.z; q7 += wi*eb.w;
    }

#pragma unroll
    for (int l = 0; l < L; ++l) {
        const int f = featp[i * L + l];
        const uint4 r = *(const uint4*)(ftab16 + (size_t)f * DIM + d0);
        const float wp = wlP[(l + 1) * NS + sg];
        const float wi = wlI[(l + 1) * NS + sg];
        float x0 = __uint_as_float(r.x << 16), x1 = __uint_as_float(r.x & 0xFFFF0000u);
        float x2 = __uint_as_float(r.y << 16), x3 = __uint_as_float(r.y & 0xFFFF0000u);
        float x4 = __uint_as_float(r.z << 16), x5 = __uint_as_float(r.z & 0xFFFF0000u);
        float x6 = __uint_as_float(r.w << 16), x7 = __uint_as_float(r.w & 0xFFFF0000u);
        p0 += wp*x0; p1 += wp*x1; p2 += wp*x2; p3 += wp*x3;
        p4 += wp*x4; p5 += wp*x5; p6 += wp*x6; p7 += wp*x7;
        q0 += wi*x0; q1 += wi*x1; q2 += wi*x2; q3 += wi*x3;
        q4 += wi*x4; q5 += wi*x5; q6 += wi*x6; q7 += wi*x7;
    }

    const float rh = rinvH[sg], rc = rinvC[sg];
    float4 oa, ob;
    oa.x = p0*rh; oa.y = p1*rh; oa.z = p2*rh; oa.w = p3*rh;
    ob.x = p4*rh; ob.y = p5*rh; ob.z = p6*rh; ob.w = p7*rh;
    *(float4*)(poolH + (size_t)i * DIM + d0)     = oa;
    *(float4*)(poolH + (size_t)i * DIM + d0 + 4) = ob;
    oa.x = q0*rc; oa.y = q1*rc; oa.z = q2*rc; oa.w = q3*rc;
    ob.x = q4*rc; ob.y = q5*rc; ob.z = q6*rc; ob.w = q7*rc;
    *(float4*)(poolC + (size_t)i * DIM + d0)     = oa;
    *(float4*)(poolC + (size_t)i * DIM + d0 + 4) = ob;
}

// ---------------------------------------------------------------------------
// k_AB: 640 blocks x 512 threads.
//   blocks [0,256)   : FUSED VAE (enc -> mu/lv -> z -> dec + partials)
//   blocks [256,640) : pool-P, 32 samples/block (4 per wave)
// ---------------------------------------------------------------------------
__global__ __launch_bounds__(512) void k_AB(
    const int* __restrict__ user_idx, const int* __restrict__ user_feat,
    const int* __restrict__ pos_idx,  const int* __restrict__ pos_feat,
    const int* __restrict__ neg_idx,  const int* __restrict__ neg_feat,
    const int* __restrict__ comp_idx,
    const float* __restrict__ emb_user, const float* __restrict__ emb_item,
    const float* __restrict__ ef_item,
    const float* __restrict__ eps,
    const float* __restrict__ enc_b, const float* __restrict__ dec_b,
    const float* __restrict__ fc11_b, const float* __restrict__ fc12_b,
    const short* __restrict__ encWT, const short* __restrict__ decWT,
    const short* __restrict__ fc11WT, const short* __restrict__ fc12WT,
    const short* __restrict__ ef16, const short* __restrict__ efU16,
    const float* __restrict__ wlP, const float* __restrict__ wlI,
    const float* __restrict__ rinvH, const float* __restrict__ rinvC,
    float* __restrict__ pooled, float* __restrict__ vae_part)
{
    __shared__ int   featsL[320];
    __shared__ int   spi[16], sci[16];
    __shared__ __align__(16) short hlds[2048];
    __shared__ float xbuf[16][128];
    __shared__ float sdots[4][16][3];
    __shared__ float red[512];

    const int t    = threadIdx.x;
    const int w    = t >> 6;
    const int lane = t & 63;
    const int g    = lane >> 4;
    const int q    = lane & 15;
    const size_t SEC = (size_t)BATCH * DIM;

    if (blockIdx.x >= 256) {
        // ============== POOL-P BLOCKS (weighted sum only) ==============
        const int p    = blockIdx.x - 256;     // [0,384)
        const int br   = p / 128;
        const int i    = (p % 128) * 32 + w * 4 + (lane >> 4);
        const int c    = lane & 15;
        const int sg   = br * 4096 + i;
        if (br == 0) {
            pool_p<LU>(user_idx, user_feat, emb_user,
                       (const unsigned short*)efU16, wlP, wlI, rinvH, rinvC,
                       pooled + 0 * SEC, pooled + 1 * SEC, i, sg, c);
        } else if (br == 1) {
            pool_p<LI>(pos_idx, pos_feat, emb_item,
                       (const unsigned short*)ef16, wlP, wlI, rinvH, rinvC,
                       pooled + 2 * SEC, pooled + 3 * SEC, i, sg, c);
        } else {
            pool_p<LI>(neg_idx, neg_feat, emb_item,
                       (const unsigned short*)ef16, wlP, wlI, rinvH, rinvC,
                       pooled + 4 * SEC, pooled + 5 * SEC, i, sg, c);
        }
        return;
    }

    // ====================== FUSED VAE BLOCKS ======================
    const int i0   = blockIdx.x * 16;
    const int wcol = w & 3;
    const int wpar = w >> 2;

    if (t < 16)      spi[t] = pos_idx[i0 + t];
    else if (t < 32) sci[t - 16] = comp_idx[i0 + t - 16];
    if (t < 320) featsL[t] = pos_feat[i0 * LI + t];
    __syncthreads();

    const int j0 = wcol * 32 + q;
    const int j1 = j0 + 16;
    const short* bbase0 = encWT + (size_t)j0 * 2560 + g * 8;
    const short* bbase1 = encWT + (size_t)j1 * 2560 + g * 8;

    f32x4 acc0 = {0.f, 0.f, 0.f, 0.f};
    f32x4 acc1 = {0.f, 0.f, 0.f, 0.f};
    for (int l = wpar; l < LI; l += 2) {
        const int f = featsL[q * LI + l];
        const short* arow = ef16 + (size_t)f * DIM + g * 8;
#pragma unroll
        for (int dt = 0; dt < 4; ++dt) {
            const int koff = l * 128 + dt * 32;
            s16x8 a  = *(const s16x8*)(arow + dt * 32);
            s16x8 b0 = *(const s16x8*)(bbase0 + koff);
            s16x8 b1 = *(const s16x8*)(bbase1 + koff);
            acc0 = __builtin_amdgcn_mfma_f32_16x16x32_bf16(a, b0, acc0, 0, 0, 0);
            acc1 = __builtin_amdgcn_mfma_f32_16x16x32_bf16(a, b1, acc1, 0, 0, 0);
        }
    }

    if (wpar == 1) {
#pragma unroll
        for (int r = 0; r < 4; ++r) {
            int s = g * 4 + r;
            xbuf[s][j0] = acc0[r];
            xbuf[s][j1] = acc1[r];
        }
    }
    __syncthreads();
    if (wpar == 0) {
        float eb0 = enc_b[j0], eb1 = enc_b[j1];
#pragma unroll
        for (int r = 0; r < 4; ++r) {
            int s = g * 4 + r;
            float h0 = acc0[r] + xbuf[s][j0] + eb0; h0 = h0 > 0.f ? h0 : 0.f;
            float h1 = acc1[r] + xbuf[s][j1] + eb1; h1 = h1 > 0.f ? h1 : 0.f;
            int swz = (s & 7) << 3;
            hlds[(s * 128 + j0) ^ swz] = f2bf(h0);
            hlds[(s * 128 + j1) ^ swz] = f2bf(h1);
        }
    }
    __syncthreads();

    const short* WT  = (wpar == 0) ? fc11WT : fc12WT;
    const short* fb0 = WT + (size_t)j0 * DIM + g * 8;
    const short* fb1 = WT + (size_t)j1 * DIM + g * 8;
    f32x4 r0v = {0.f,0.f,0.f,0.f}, r1v = {0.f,0.f,0.f,0.f};
#pragma unroll
    for (int kt = 0; kt < 4; ++kt) {
        int sidx = (q * 128 + kt * 32 + g * 8) ^ ((q & 7) << 3);
        s16x8 a  = *(const s16x8*)&hlds[sidx];
        s16x8 w0 = *(const s16x8*)(fb0 + kt * 32);
        s16x8 w1 = *(const s16x8*)(fb1 + kt * 32);
        r0v = __builtin_amdgcn_mfma_f32_16x16x32_bf16(a, w0, r0v, 0, 0, 0);
        r1v = __builtin_amdgcn_mfma_f32_16x16x32_bf16(a, w1, r1v, 0, 0, 0);
    }
    if (wpar == 1) {
        float b12_0 = fc12_b[j0], b12_1 = fc12_b[j1];
#pragma unroll
        for (int r = 0; r < 4; ++r) {
            int s = g * 4 + r;
            xbuf[s][j0] = r0v[r] + b12_0;
            xbuf[s][j1] = r1v[r] + b12_1;
        }
    }
    __syncthreads();

    float kacc = 0.f;
    if (wpar == 0) {
        float b11_0 = fc11_b[j0], b11_1 = fc11_b[j1];
#pragma unroll
        for (int r = 0; r < 4; ++r) {
            const int s = g * 4 + r;
            const int i = i0 + s;
            float m0 = r0v[r] + b11_0, m1 = r1v[r] + b11_1;
            float v0 = xbuf[s][j0],  v1 = xbuf[s][j1];
            float e0 = eps[(size_t)i * DIM + j0];
            float e1 = eps[(size_t)i * DIM + j1];
            float z0 = e0 * expf(0.5f * v0) + m0;
            float z1 = e1 * expf(0.5f * v1) + m1;
            int swz = (s & 7) << 3;
            hlds[(s * 128 + j0) ^ swz] = f2bf(z0);
            hlds[(s * 128 + j1) ^ swz] = f2bf(z1);
            kacc += (1.f + v0 - m0 * m0 - expf(v0)) + (1.f + v1 - m1 * m1 - expf(v1));

            const size_t pb2 = (size_t)spi[s] * DIM;
            const size_t cb2 = (size_t)sci[s] * DIM;
            float pe0 = emb_item[pb2 + j0], pe1 = emb_item[pb2 + j1];
            float ce0 = emb_item[cb2 + j0], ce1 = emb_item[cb2 + j1];
            float zp = z0 * pe0 + z1 * pe1;
            float zc = z0 * ce0 + z1 * ce1;
            float d0 = z0 - pe0, d1 = z1 - pe1;
            float zq = d0 * d0 + d1 * d1;
            for (int mm = 8; mm >= 1; mm >>= 1) {
                zp += __shfl_xor(zp, mm, 64);
                zc += __shfl_xor(zc, mm, 64);
                zq += __shfl_xor(zq, mm, 64);
            }
            if (q == 0) {
                sdots[w][s][0] = zp;
                sdots[w][s][1] = zc;
                sdots[w][s][2] = zq;
            }
        }
    }
    __syncthreads();

    // decoder + mse (all 8 waves)
    s16x8 za[4];
#pragma unroll
    for (int kt = 0; kt < 4; ++kt)
        za[kt] = *(const s16x8*)&hlds[(q * 128 + kt * 32 + g * 8) ^ ((q & 7) << 3)];

    const int cw = w * 320;
    float macc = 0.f;
    for (int fp = 0; fp < 10; ++fp) {
        const int c0 = cw + fp * 32 + q;
        const int c1 = c0 + 16;
        const short* bp0 = decWT + (size_t)c0 * DIM + g * 8;
        const short* bp1 = decWT + (size_t)c1 * DIM + g * 8;
        s16x8 b0[4], b1[4];
#pragma unroll
        for (int kt = 0; kt < 4; ++kt) {
            b0[kt] = *(const s16x8*)(bp0 + kt * 32);
            b1[kt] = *(const s16x8*)(bp1 + kt * 32);
        }
        const int l0 = c0 >> 7, d0 = c0 & 127;
        const int l1 = c1 >> 7, d1 = c1 & 127;
        float x0[4], x1[4];
#pragma unroll
        for (int r = 0; r < 4; ++r) {
            x0[r] = ef_item[(size_t)featsL[(g * 4 + r) * LI + l0] * DIM + d0];
            x1[r] = ef_item[(size_t)featsL[(g * 4 + r) * LI + l1] * DIM + d1];
        }
        const float bias0 = dec_b[c0], bias1 = dec_b[c1];
        f32x4 a0 = {0.f,0.f,0.f,0.f}, a1 = {0.f,0.f,0.f,0.f};
#pragma unroll
        for (int kt = 0; kt < 4; ++kt) {
            a0 = __builtin_amdgcn_mfma_f32_16x16x32_bf16(za[kt], b0[kt], a0, 0, 0, 0);
            a1 = __builtin_amdgcn_mfma_f32_16x16x32_bf16(za[kt], b1[kt], a1, 0, 0, 0);
        }
#pragma unroll
        for (int r = 0; r < 4; ++r) {
            float dd0 = a0[r] + bias0 - x0[r];
            float dd1 = a1[r] + bias1 - x1[r];
            macc += dd0 * dd0 + dd1 * dd1;
        }
    }

    red[t] = 0.05f * macc + ((wpar == 0) ? -0.5f * kacc : 0.f);  // mse/LI
    __syncthreads();
    if (t < 16) {
        float zp = 0.f, zc = 0.f, zq = 0.f;
        for (int ww = 0; ww < 4; ++ww) {
            zp += sdots[ww][t][0];
            zc += sdots[ww][t][1];
            zq += sdots[ww][t][2];
        }
        float x = zp - zc;
        float ls = (x >= 0.f) ? -log1pf(expf(-x)) : (x - log1pf(expf(x)));
        red[t] += -ls + zq;
    }
    __syncthreads();
    for (int off = 256; off > 0; off >>= 1) {
        if (t < off) red[t] += red[t + off];
        __syncthreads();
    }
    if (t == 0) vae_part[blockIdx.x] = red[0];
}

// ---------------------------------------------------------------------------
// k_loss: 256 blocks x 256 threads — triplet losses via MFMA; block 0 also
// reduces vae_part -> item_vae_loss scalar.
// ---------------------------------------------------------------------------
__global__ __launch_bounds__(256) void k_loss(
    const float* __restrict__ pooled,
    const short* __restrict__ wpopT, const short* __restrict__ wintT,
    const float* __restrict__ vae_part,
    float* __restrict__ out_hot, float* __restrict__ out_cold,
    float* __restrict__ out_scalar)
{
    __shared__ float sArr[4][16];
    __shared__ float red[256];

    const int t    = threadIdx.x;
    const int w    = t >> 6;
    const int lane = t & 63;
    const int g    = lane >> 4;
    const int q    = lane & 15;
    const int i0   = blockIdx.x * 16;

    const int h     = w >> 1;
    const int other = (w & 1) + 1;
    const float* pu = pooled + (size_t)(0 * 2 + h) * BATCH * DIM;
    const float* po = pooled + (size_t)(other * 2 + h) * BATCH * DIM;
    const short* wT = h ? wintT : wpopT;

    s16x8 afr[4];
#pragma unroll
    for (int kt = 0; kt < 4; ++kt) {
        const size_t off = (size_t)(i0 + q) * DIM + kt * 32 + g * 8;
        f32x4 ua = *(const f32x4*)(pu + off);
        f32x4 ub = *(const f32x4*)(pu + off + 4);
        f32x4 oa = *(const f32x4*)(po + off);
        f32x4 ob = *(const f32x4*)(po + off + 4);
        s16x8 v;
        v[0] = f2bf(ua[0] - oa[0]); v[1] = f2bf(ua[1] - oa[1]);
        v[2] = f2bf(ua[2] - oa[2]); v[3] = f2bf(ua[3] - oa[3]);
        v[4] = f2bf(ub[0] - ob[0]); v[5] = f2bf(ub[1] - ob[1]);
        v[6] = f2bf(ub[2] - ob[2]); v[7] = f2bf(ub[3] - ob[3]);
        afr[kt] = v;
    }

    float sq0 = 0.f, sq1 = 0.f, sq2 = 0.f, sq3 = 0.f;
    for (int fr = 0; fr < 8; ++fr) {
        const short* bb = wT + (size_t)(fr * 16 + q) * DIM + g * 8;
        f32x4 acc = {0.f, 0.f, 0.f, 0.f};
#pragma unroll
        for (int kt = 0; kt < 4; ++kt) {
            s16x8 bfr = *(const s16x8*)(bb + kt * 32);
            acc = __builtin_amdgcn_mfma_f32_16x16x32_bf16(afr[kt], bfr, acc, 0, 0, 0);
        }
        sq0 += acc[0] * acc[0]; sq1 += acc[1] * acc[1];
        sq2 += acc[2] * acc[2]; sq3 += acc[3] * acc[3];
    }
    for (int m = 8; m >= 1; m >>= 1) {
        sq0 += __shfl_xor(sq0, m, 64);
        sq1 += __shfl_xor(sq1, m, 64);
        sq2 += __shfl_xor(sq2, m, 64);
        sq3 += __shfl_xor(sq3, m, 64);
    }
    if (q == 0) {
        sArr[w][g * 4 + 0] = sq0;
        sArr[w][g * 4 + 1] = sq1;
        sArr[w][g * 4 + 2] = sq2;
        sArr[w][g * 4 + 3] = sq3;
    }
    __syncthreads();
    if (t < 16) {
        float v = sArr[0][t] - sArr[1][t] + 1.0f;
        out_hot[i0 + t] = v > 0.f ? v : 0.f;
    } else if (t < 32) {
        int s = t - 16;
        float v = sArr[2][s] - sArr[3][s] + 1.0f;
        out_cold[i0 + s] = v > 0.f ? v : 0.f;
    }

    if (blockIdx.x == 0) {
        red[t] = vae_part[t];
        __syncthreads();
        for (int off = 128; off > 0; off >>= 1) {
            if (t < off) red[t] += red[t + off];
            __syncthreads();
        }
        if (t == 0) out_scalar[0] = red[0];
    }
}

// ---------------------------------------------------------------------------
extern "C" void kernel_launch(void* const* d_in, const int* in_sizes, int n_in,
                              void* d_out, int out_size, void* d_ws, size_t ws_size,
                              hipStream_t stream) {
    const int*   user_idx  = (const int*)d_in[0];
    const int*   user_feat = (const int*)d_in[1];
    const int*   pos_idx   = (const int*)d_in[2];
    const int*   pos_feat  = (const int*)d_in[3];
    const int*   neg_idx   = (const int*)d_in[4];
    const int*   neg_feat  = (const int*)d_in[5];
    const int*   comp_idx  = (const int*)d_in[6];
    const float* eps       = (const float*)d_in[7];
    const float* emb_user  = (const float*)d_in[8];
    const float* emb_item  = (const float*)d_in[9];
    const float* ef_user   = (const float*)d_in[10];
    const float* ef_item   = (const float*)d_in[11];
    const float* pop_u     = (const float*)d_in[12];
    const float* int_u     = (const float*)d_in[13];
    const float* pop_i     = (const float*)d_in[14];
    const float* int_i     = (const float*)d_in[15];
    const float* W_pop     = (const float*)d_in[16];
    const float* W_int     = (const float*)d_in[18];
    const float* enc_W     = (const float*)d_in[20];
    const float* enc_b     = (const float*)d_in[21];
    const float* dec_W     = (const float*)d_in[22];
    const float* dec_b     = (const float*)d_in[23];
    const float* fc11_W    = (const float*)d_in[24];
    const float* fc11_b    = (const float*)d_in[25];
    const float* fc12_W    = (const float*)d_in[26];
    const float* fc12_b    = (const float*)d_in[27];

    float* out = (float*)d_out;
    char*  ws  = (char*)d_ws;

    short* encWT    = (short*)(ws);                    //   655,360 B
    short* decWT    = (short*)(ws + 655360);           //   655,360
    short* fc11WT   = (short*)(ws + 1310720);          //    32,768
    short* fc12WT   = (short*)(ws + 1343488);          //    32,768
    short* wpopT    = (short*)(ws + 1376256);          //    32,768
    short* wintT    = (short*)(ws + 1409024);          //    32,768
    short* ef16     = (short*)(ws + 1441792);          // 1,280,000
    short* efU16    = (short*)(ws + 2721792);          //   512,000
    float* pooled   = (float*)(ws + 4282368);          // 12,582,912
    float* vae_part = (float*)(ws + 16865280);         //     1,024
    float* projIP   = (float*)(ws + 16874496);         //    20,000
    float* projII   = (float*)(ws + 16894496);         //    20,000
    float* projUP   = (float*)(ws + 16914496);         //     8,000
    float* projUI   = (float*)(ws + 16922496);         //     8,000
    float* sEP      = (float*)(ws + 16930496);         //    49,152
    float* sEI      = (float*)(ws + 16979648);         //    49,152
    float* wlP      = (float*)(ws + 17028800);         // 1,032,192
    float* wlI      = (float*)(ws + 18060992);         // 1,032,192
    float* rinvH    = (float*)(ws + 19093184);         //    49,152
    float* rinvC    = (float*)(ws + 19142336);         //    49,152

    k_prep<<<dim3(2838), dim3(256), 0, stream>>>(
        enc_W, dec_W, fc11_W, fc12_W, W_pop, W_int, ef_item, ef_user,
        pop_i, int_i, pop_u, int_u,
        user_idx, pos_idx, neg_idx, emb_user, emb_item,
        encWT, decWT, fc11WT, fc12WT, wpopT, wintT, ef16, efU16,
        projIP, projII, projUP, projUI, sEP, sEI);

    k_W<<<dim3(48), dim3(256), 0, stream>>>(
        user_feat, pos_feat, neg_feat,
        projIP, projII, projUP, projUI, sEP, sEI,
        wlP, wlI, rinvH, rinvC);

    k_AB<<<dim3(640), dim3(512), 0, stream>>>(
        user_idx, user_feat, pos_idx, pos_feat, neg_idx, neg_feat, comp_idx,
        emb_user, emb_item, ef_item,
        eps, enc_b, dec_b, fc11_b, fc12_b,
        encWT, decWT, fc11WT, fc12WT, ef16, efU16,
        wlP, wlI, rinvH, rinvC,
        pooled, vae_part);

    k_loss<<<dim3(256), dim3(256), 0, stream>>>(
        pooled, wpopT, wintT, vae_part,
        out, out + BATCH, out + 2 * BATCH);
}

// Round 17
// 74.595 us; speedup vs baseline: 1.2624x; 1.2624x over previous
//
#include <hip/hip_runtime.h>
#include <math.h>

#define BATCH 4096
#define DIM 128
#define LU 10
#define LI 20

typedef float  f32x4  __attribute__((ext_vector_type(4)));
typedef short  s16x8  __attribute__((ext_vector_type(8)));
typedef unsigned short u16x8 __attribute__((ext_vector_type(8)));

// round-to-nearest-even fp32 -> bf16
__device__ __forceinline__ short f2bf(float x) {
    unsigned u = __float_as_uint(x);
    u += 0x7FFFu + ((u >> 16) & 1u);
    return (short)(u >> 16);
}
__device__ __forceinline__ float bf2f(unsigned short u) {
    return __uint_as_float(((unsigned)u) << 16);
}
// pack two fp32 -> one u32 of 2 bf16 (lo = first)
__device__ __forceinline__ unsigned pk2bf(float a, float b) {
    return (unsigned)(unsigned short)f2bf(a) | ((unsigned)(unsigned short)f2bf(b) << 16);
}

// ---------------------------------------------------------------------------
// K_prep: transpose+convert weights to bf16; ef tables to bf16; projection
// tables proj = ef @ vec (per feature id, both vectors).
// ---------------------------------------------------------------------------
__global__ __launch_bounds__(256) void k_prep(
    const float* __restrict__ enc_W, const float* __restrict__ dec_W,
    const float* __restrict__ fc11_W, const float* __restrict__ fc12_W,
    const float* __restrict__ W_pop, const float* __restrict__ W_int,
    const float* __restrict__ ef_item, const float* __restrict__ ef_user,
    const float* __restrict__ pop_i, const float* __restrict__ int_i,
    const float* __restrict__ pop_u, const float* __restrict__ int_u,
    short* __restrict__ encWT, short* __restrict__ decWT,
    short* __restrict__ fc11WT, short* __restrict__ fc12WT,
    short* __restrict__ wpopT, short* __restrict__ wintT,
    short* __restrict__ ef16, short* __restrict__ efU16,
    float* __restrict__ projIP, float* __restrict__ projII,
    float* __restrict__ projUP, float* __restrict__ projUI)
{
    __shared__ float tile[32][33];
    const int b = blockIdx.x;
    const int t = threadIdx.x;

    if (b < 704) {
        const float* src; short* dst; int r0, c0, src_ld, dst_ld;
        if (b < 320) {
            int tk = b % 80, tj = b / 80;
            src = enc_W; dst = encWT; r0 = tk * 32; c0 = tj * 32; src_ld = 128; dst_ld = 2560;
        } else if (b < 640) {
            int tb = b - 320; int tc = tb % 80, td = tb / 80;
            src = dec_W; dst = decWT; r0 = td * 32; c0 = tc * 32; src_ld = 2560; dst_ld = 128;
        } else if (b < 656) {
            int tb = b - 640; int tk = tb % 4, tj = tb / 4;
            src = fc11_W; dst = fc11WT; r0 = tk * 32; c0 = tj * 32; src_ld = 128; dst_ld = 128;
        } else if (b < 672) {
            int tb = b - 656; int tk = tb % 4, tj = tb / 4;
            src = fc12_W; dst = fc12WT; r0 = tk * 32; c0 = tj * 32; src_ld = 128; dst_ld = 128;
        } else if (b < 688) {
            int tb = b - 672; int tk = tb % 4, tj = tb / 4;
            src = W_pop; dst = wpopT; r0 = tk * 32; c0 = tj * 32; src_ld = 128; dst_ld = 128;
        } else {
            int tb = b - 688; int tk = tb % 4, tj = tb / 4;
            src = W_int; dst = wintT; r0 = tk * 32; c0 = tj * 32; src_ld = 128; dst_ld = 128;
        }
        for (int q = 0; q < 4; ++q) {
            int e = t + q * 256;
            int r = e >> 5, c = e & 31;
            tile[r][c] = src[(size_t)(r0 + r) * src_ld + (c0 + c)];
        }
        __syncthreads();
        for (int q = 0; q < 4; ++q) {
            int e = t + q * 256;
            int r = e >> 5, c = e & 31;
            dst[(size_t)(c0 + r) * dst_ld + (r0 + c)] = f2bf(tile[c][r]);
        }
    } else if (b < 1329) {
        int base = (b - 704) * 1024 + t * 4;
        float4 v = *(const float4*)(ef_item + base);
        short4 o;
        o.x = f2bf(v.x); o.y = f2bf(v.y); o.z = f2bf(v.z); o.w = f2bf(v.w);
        *(short4*)(ef16 + base) = o;
    } else if (b < 1579) {
        int base = (b - 1329) * 1024 + t * 4;
        float4 v = *(const float4*)(ef_user + base);
        short4 o;
        o.x = f2bf(v.x); o.y = f2bf(v.y); o.z = f2bf(v.z); o.w = f2bf(v.w);
        *(short4*)(efU16 + base) = o;
    } else {
        const int pb = b - 1579;
        const float* tab; const float* v0p; const float* v1p;
        float* o0; float* o1; int row;
        if (pb < 625) {
            row = pb * 8 + (t >> 5);
            tab = ef_item; v0p = pop_i; v1p = int_i; o0 = projIP; o1 = projII;
        } else {
            row = (pb - 625) * 8 + (t >> 5);
            tab = ef_user; v0p = pop_u; v1p = int_u; o0 = projUP; o1 = projUI;
        }
        const int d = (t & 31) * 4;
        float4 rv = *(const float4*)(tab + (size_t)row * DIM + d);
        float4 a  = *(const float4*)(v0p + d);
        float4 c  = *(const float4*)(v1p + d);
        float s0 = rv.x * a.x + rv.y * a.y + rv.z * a.z + rv.w * a.w;
        float s1 = rv.x * c.x + rv.y * c.y + rv.z * c.z + rv.w * c.w;
        s0 += __shfl_xor(s0, 1, 64);  s1 += __shfl_xor(s1, 1, 64);
        s0 += __shfl_xor(s0, 2, 64);  s1 += __shfl_xor(s1, 2, 64);
        s0 += __shfl_xor(s0, 4, 64);  s1 += __shfl_xor(s1, 4, 64);
        s0 += __shfl_xor(s0, 8, 64);  s1 += __shfl_xor(s1, 8, 64);
        s0 += __shfl_xor(s0, 16, 64); s1 += __shfl_xor(s1, 16, 64);
        if ((t & 31) == 0) { o0[row] = s0; o1[row] = s1; }
    }
}

// ---------------------------------------------------------------------------
// pool_sc<L>: ONE WAVE per (sample, branch). Feature scores from projection
// tables (wave-uniform scalar loads); entity row: one butterfly. Rows in
// registers (bf16 packed), single pass. OUTPUT: bf16-packed pooled.
// ---------------------------------------------------------------------------
template<int L>
__device__ __forceinline__ void pool_sc(
    const int* __restrict__ idxp, const int* __restrict__ featp,
    const float* __restrict__ etab, const unsigned short* __restrict__ ftab16,
    const float* __restrict__ projP, const float* __restrict__ projI,
    const float* __restrict__ vpop, const float* __restrict__ vint,
    unsigned short* __restrict__ poolH, unsigned short* __restrict__ poolC,
    int i_in, int lane)
{
    const int i = __builtin_amdgcn_readfirstlane(i_in);
    const int d = lane * 2;

    int fidx[L];
#pragma unroll
    for (int l = 0; l < L; ++l) fidx[l] = featp[i * L + l];
    const int idx0 = idxp[i];

    const float2 e0 = *(const float2*)(etab + (size_t)idx0 * DIM + d);
    unsigned rr[L];
#pragma unroll
    for (int l = 0; l < L; ++l)
        rr[l] = *(const unsigned*)(ftab16 + (size_t)fidx[l] * DIM + d);

    float sp[L + 1], si[L + 1];
#pragma unroll
    for (int l = 0; l < L; ++l) {
        sp[l + 1] = projP[fidx[l]];
        si[l + 1] = projI[fidx[l]];
    }

    {
        const float2 vp = *(const float2*)(vpop + d);
        const float2 vi = *(const float2*)(vint + d);
        float aH = e0.x * vp.x + e0.y * vp.y;
        float aC = e0.x * vi.x + e0.y * vi.y;
        aH += __shfl_xor(aH, 1, 64);  aC += __shfl_xor(aC, 1, 64);
        aH += __shfl_xor(aH, 2, 64);  aC += __shfl_xor(aC, 2, 64);
        aH += __shfl_xor(aH, 4, 64);  aC += __shfl_xor(aC, 4, 64);
        aH += __shfl_xor(aH, 8, 64);  aC += __shfl_xor(aC, 8, 64);
        aH += __shfl_xor(aH, 16, 64); aC += __shfl_xor(aC, 16, 64);
        aH += __shfl_xor(aH, 32, 64); aC += __shfl_xor(aC, 32, 64);
        sp[0] = aH; si[0] = aC;
    }

    unsigned mbits = 1u;
#pragma unroll
    for (int l = 0; l < L; ++l) mbits |= (fidx[l] != 0 ? 2u : 0u) << l;

    float mh = sp[0], mc = si[0];
#pragma unroll
    for (int l = 1; l <= L; ++l) {
        bool v = (mbits >> l) & 1u;
        mh = v ? fmaxf(mh, sp[l]) : mh;
        mc = v ? fmaxf(mc, si[l]) : mc;
    }
    float sh = 0.f, sc = 0.f;
#pragma unroll
    for (int l = 0; l <= L; ++l) {
        bool v = (l == 0) | ((mbits >> l) & 1u);
        float eh = v ? __expf(sp[l] - mh) : 0.f;
        float ec = v ? __expf(si[l] - mc) : 0.f;
        sp[l] = eh; si[l] = ec;
        sh += eh; sc += ec;
    }
    const float rh = 1.f / sh, rc = 1.f / sc;

    float hx = sp[0] * e0.x, hy = sp[0] * e0.y;
    float cx = si[0] * e0.x, cy = si[0] * e0.y;
#pragma unroll
    for (int l = 0; l < L; ++l) {
        float x = __uint_as_float(rr[l] << 16);
        float y = __uint_as_float(rr[l] & 0xFFFF0000u);
        hx += sp[l + 1] * x; hy += sp[l + 1] * y;
        cx += si[l + 1] * x; cy += si[l + 1] * y;
    }
    *(unsigned*)(poolH + (size_t)i * DIM + d) = pk2bf(hx * rh, hy * rh);
    *(unsigned*)(poolC + (size_t)i * DIM + d) = pk2bf(cx * rc, cy * rc);
}

// ---------------------------------------------------------------------------
// k_AB: 1792 blocks x 512 threads.
//   blocks [0,256)    : FUSED VAE (enc -> mu/lv -> z -> dec + partials)
//   blocks [256,1792) : pooling, 8 waves = 8 samples per block
// ---------------------------------------------------------------------------
__global__ __launch_bounds__(512) void k_AB(
    const int* __restrict__ user_idx, const int* __restrict__ user_feat,
    const int* __restrict__ pos_idx,  const int* __restrict__ pos_feat,
    const int* __restrict__ neg_idx,  const int* __restrict__ neg_feat,
    const int* __restrict__ comp_idx,
    const float* __restrict__ emb_user, const float* __restrict__ emb_item,
    const float* __restrict__ ef_item,
    const float* __restrict__ pop_u, const float* __restrict__ int_u,
    const float* __restrict__ pop_i, const float* __restrict__ int_i,
    const float* __restrict__ eps,
    const float* __restrict__ enc_b, const float* __restrict__ dec_b,
    const float* __restrict__ fc11_b, const float* __restrict__ fc12_b,
    const short* __restrict__ encWT, const short* __restrict__ decWT,
    const short* __restrict__ fc11WT, const short* __restrict__ fc12WT,
    const short* __restrict__ ef16, const short* __restrict__ efU16,
    const float* __restrict__ projIP, const float* __restrict__ projII,
    const float* __restrict__ projUP, const float* __restrict__ projUI,
    unsigned short* __restrict__ pooled, float* __restrict__ vae_part)
{
    __shared__ int   featsL[320];
    __shared__ int   spi[16], sci[16];
    __shared__ __align__(16) short hlds[2048];
    __shared__ float xbuf[16][128];
    __shared__ float sdots[4][16][3];
    __shared__ float red[512];

    const int t    = threadIdx.x;
    const int w    = t >> 6;
    const int lane = t & 63;
    const int g    = lane >> 4;
    const int q    = lane & 15;
    const size_t SEC = (size_t)BATCH * DIM;

    if (blockIdx.x >= 256) {
        const int pb = blockIdx.x - 256;       // [0,1536)
        const int br = pb % 3;                 // 0 user, 1 pos, 2 neg
        const int i  = (pb / 3) * 8 + w;
        if (br == 0) {
            pool_sc<LU>(user_idx, user_feat, emb_user,
                        (const unsigned short*)efU16, projUP, projUI,
                        pop_u, int_u,
                        pooled + 0 * SEC, pooled + 1 * SEC, i, lane);
        } else if (br == 1) {
            pool_sc<LI>(pos_idx, pos_feat, emb_item,
                        (const unsigned short*)ef16, projIP, projII,
                        pop_i, int_i,
                        pooled + 2 * SEC, pooled + 3 * SEC, i, lane);
        } else {
            pool_sc<LI>(neg_idx, neg_feat, emb_item,
                        (const unsigned short*)ef16, projIP, projII,
                        pop_i, int_i,
                        pooled + 4 * SEC, pooled + 5 * SEC, i, lane);
        }
        return;
    }

    // ====================== FUSED VAE BLOCKS ======================
    const int i0   = blockIdx.x * 16;
    const int wcol = w & 3;
    const int wpar = w >> 2;

    if (t < 16)      spi[t] = pos_idx[i0 + t];
    else if (t < 32) sci[t - 16] = comp_idx[i0 + t - 16];
    if (t < 320) featsL[t] = pos_feat[i0 * LI + t];
    __syncthreads();

    const int j0 = wcol * 32 + q;
    const int j1 = j0 + 16;
    const short* bbase0 = encWT + (size_t)j0 * 2560 + g * 8;
    const short* bbase1 = encWT + (size_t)j1 * 2560 + g * 8;

    f32x4 acc0 = {0.f, 0.f, 0.f, 0.f};
    f32x4 acc1 = {0.f, 0.f, 0.f, 0.f};
    for (int l = wpar; l < LI; l += 2) {
        const int f = featsL[q * LI + l];
        const short* arow = ef16 + (size_t)f * DIM + g * 8;
#pragma unroll
        for (int dt = 0; dt < 4; ++dt) {
            const int koff = l * 128 + dt * 32;
            s16x8 a  = *(const s16x8*)(arow + dt * 32);
            s16x8 b0 = *(const s16x8*)(bbase0 + koff);
            s16x8 b1 = *(const s16x8*)(bbase1 + koff);
            acc0 = __builtin_amdgcn_mfma_f32_16x16x32_bf16(a, b0, acc0, 0, 0, 0);
            acc1 = __builtin_amdgcn_mfma_f32_16x16x32_bf16(a, b1, acc1, 0, 0, 0);
        }
    }

    if (wpar == 1) {
#pragma unroll
        for (int r = 0; r < 4; ++r) {
            int s = g * 4 + r;
            xbuf[s][j0] = acc0[r];
            xbuf[s][j1] = acc1[r];
        }
    }
    __syncthreads();
    if (wpar == 0) {
        float eb0 = enc_b[j0], eb1 = enc_b[j1];
#pragma unroll
        for (int r = 0; r < 4; ++r) {
            int s = g * 4 + r;
            float h0 = acc0[r] + xbuf[s][j0] + eb0; h0 = h0 > 0.f ? h0 : 0.f;
            float h1 = acc1[r] + xbuf[s][j1] + eb1; h1 = h1 > 0.f ? h1 : 0.f;
            int swz = (s & 7) << 3;
            hlds[(s * 128 + j0) ^ swz] = f2bf(h0);
            hlds[(s * 128 + j1) ^ swz] = f2bf(h1);
        }
    }
    __syncthreads();

    const short* WT  = (wpar == 0) ? fc11WT : fc12WT;
    const short* fb0 = WT + (size_t)j0 * DIM + g * 8;
    const short* fb1 = WT + (size_t)j1 * DIM + g * 8;
    f32x4 r0v = {0.f,0.f,0.f,0.f}, r1v = {0.f,0.f,0.f,0.f};
#pragma unroll
    for (int kt = 0; kt < 4; ++kt) {
        int sidx = (q * 128 + kt * 32 + g * 8) ^ ((q & 7) << 3);
        s16x8 a  = *(const s16x8*)&hlds[sidx];
        s16x8 w0 = *(const s16x8*)(fb0 + kt * 32);
        s16x8 w1 = *(const s16x8*)(fb1 + kt * 32);
        r0v = __builtin_amdgcn_mfma_f32_16x16x32_bf16(a, w0, r0v, 0, 0, 0);
        r1v = __builtin_amdgcn_mfma_f32_16x16x32_bf16(a, w1, r1v, 0, 0, 0);
    }
    if (wpar == 1) {
        float b12_0 = fc12_b[j0], b12_1 = fc12_b[j1];
#pragma unroll
        for (int r = 0; r < 4; ++r) {
            int s = g * 4 + r;
            xbuf[s][j0] = r0v[r] + b12_0;
            xbuf[s][j1] = r1v[r] + b12_1;
        }
    }
    __syncthreads();

    float kacc = 0.f;
    if (wpar == 0) {
        float b11_0 = fc11_b[j0], b11_1 = fc11_b[j1];
#pragma unroll
        for (int r = 0; r < 4; ++r) {
            const int s = g * 4 + r;
            const int i = i0 + s;
            float m0 = r0v[r] + b11_0, m1 = r1v[r] + b11_1;
            float v0 = xbuf[s][j0],  v1 = xbuf[s][j1];
            float e0 = eps[(size_t)i * DIM + j0];
            float e1 = eps[(size_t)i * DIM + j1];
            float z0 = e0 * expf(0.5f * v0) + m0;
            float z1 = e1 * expf(0.5f * v1) + m1;
            int swz = (s & 7) << 3;
            hlds[(s * 128 + j0) ^ swz] = f2bf(z0);
            hlds[(s * 128 + j1) ^ swz] = f2bf(z1);
            kacc += (1.f + v0 - m0 * m0 - expf(v0)) + (1.f + v1 - m1 * m1 - expf(v1));

            const size_t pb2 = (size_t)spi[s] * DIM;
            const size_t cb2 = (size_t)sci[s] * DIM;
            float pe0 = emb_item[pb2 + j0], pe1 = emb_item[pb2 + j1];
            float ce0 = emb_item[cb2 + j0], ce1 = emb_item[cb2 + j1];
            float zp = z0 * pe0 + z1 * pe1;
            float zc = z0 * ce0 + z1 * ce1;
            float d0 = z0 - pe0, d1 = z1 - pe1;
            float zq = d0 * d0 + d1 * d1;
            for (int mm = 8; mm >= 1; mm >>= 1) {
                zp += __shfl_xor(zp, mm, 64);
                zc += __shfl_xor(zc, mm, 64);
                zq += __shfl_xor(zq, mm, 64);
            }
            if (q == 0) {
                sdots[w][s][0] = zp;
                sdots[w][s][1] = zc;
                sdots[w][s][2] = zq;
            }
        }
    }
    __syncthreads();

    // decoder + mse (all 8 waves): wave w handles cols [w*320, w*320+320)
    s16x8 za[4];
#pragma unroll
    for (int kt = 0; kt < 4; ++kt)
        za[kt] = *(const s16x8*)&hlds[(q * 128 + kt * 32 + g * 8) ^ ((q & 7) << 3)];

    const int cw = w * 320;
    float macc = 0.f;
    for (int fp = 0; fp < 10; ++fp) {
        const int c0 = cw + fp * 32 + q;
        const int c1 = c0 + 16;
        const short* bp0 = decWT + (size_t)c0 * DIM + g * 8;
        const short* bp1 = decWT + (size_t)c1 * DIM + g * 8;
        s16x8 b0[4], b1[4];
#pragma unroll
        for (int kt = 0; kt < 4; ++kt) {
            b0[kt] = *(const s16x8*)(bp0 + kt * 32);
            b1[kt] = *(const s16x8*)(bp1 + kt * 32);
        }
        const int l0 = c0 >> 7, d0 = c0 & 127;
        const int l1 = c1 >> 7, d1 = c1 & 127;
        float x0[4], x1[4];
#pragma unroll
        for (int r = 0; r < 4; ++r) {
            x0[r] = ef_item[(size_t)featsL[(g * 4 + r) * LI + l0] * DIM + d0];
            x1[r] = ef_item[(size_t)featsL[(g * 4 + r) * LI + l1] * DIM + d1];
        }
        const float bias0 = dec_b[c0], bias1 = dec_b[c1];
        f32x4 a0 = {0.f,0.f,0.f,0.f}, a1 = {0.f,0.f,0.f,0.f};
#pragma unroll
        for (int kt = 0; kt < 4; ++kt) {
            a0 = __builtin_amdgcn_mfma_f32_16x16x32_bf16(za[kt], b0[kt], a0, 0, 0, 0);
            a1 = __builtin_amdgcn_mfma_f32_16x16x32_bf16(za[kt], b1[kt], a1, 0, 0, 0);
        }
#pragma unroll
        for (int r = 0; r < 4; ++r) {
            float dd0 = a0[r] + bias0 - x0[r];
            float dd1 = a1[r] + bias1 - x1[r];
            macc += dd0 * dd0 + dd1 * dd1;
        }
    }

    red[t] = 0.05f * macc + ((wpar == 0) ? -0.5f * kacc : 0.f);  // mse/LI
    __syncthreads();
    if (t < 16) {
        float zp = 0.f, zc = 0.f, zq = 0.f;
        for (int ww = 0; ww < 4; ++ww) {
            zp += sdots[ww][t][0];
            zc += sdots[ww][t][1];
            zq += sdots[ww][t][2];
        }
        float x = zp - zc;
        float ls = (x >= 0.f) ? -log1pf(expf(-x)) : (x - log1pf(expf(x)));
        red[t] += -ls + zq;
    }
    __syncthreads();
    for (int off = 256; off > 0; off >>= 1) {
        if (t < off) red[t] += red[t + off];
        __syncthreads();
    }
    if (t == 0) vae_part[blockIdx.x] = red[0];
}

// ---------------------------------------------------------------------------
// k_loss: 256 blocks x 256 threads — triplet losses via MFMA from bf16
// pooled; block 0 also reduces vae_part -> item_vae_loss scalar.
// ---------------------------------------------------------------------------
__global__ __launch_bounds__(256) void k_loss(
    const unsigned short* __restrict__ pooled,
    const short* __restrict__ wpopT, const short* __restrict__ wintT,
    const float* __restrict__ vae_part,
    float* __restrict__ out_hot, float* __restrict__ out_cold,
    float* __restrict__ out_scalar)
{
    __shared__ float sArr[4][16];
    __shared__ float red[256];

    const int t    = threadIdx.x;
    const int w    = t >> 6;
    const int lane = t & 63;
    const int g    = lane >> 4;
    const int q    = lane & 15;
    const int i0   = blockIdx.x * 16;

    const int h     = w >> 1;
    const int other = (w & 1) + 1;
    const unsigned short* pu = pooled + (size_t)(0 * 2 + h) * BATCH * DIM;
    const unsigned short* po = pooled + (size_t)(other * 2 + h) * BATCH * DIM;
    const short* wT = h ? wintT : wpopT;

    s16x8 afr[4];
#pragma unroll
    for (int kt = 0; kt < 4; ++kt) {
        const size_t off = (size_t)(i0 + q) * DIM + kt * 32 + g * 8;
        u16x8 ua = *(const u16x8*)(pu + off);
        u16x8 oa = *(const u16x8*)(po + off);
        s16x8 v;
#pragma unroll
        for (int e = 0; e < 8; ++e)
            v[e] = f2bf(bf2f(ua[e]) - bf2f(oa[e]));
        afr[kt] = v;
    }

    float sq0 = 0.f, sq1 = 0.f, sq2 = 0.f, sq3 = 0.f;
    for (int fr = 0; fr < 8; ++fr) {
        const short* bb = wT + (size_t)(fr * 16 + q) * DIM + g * 8;
        f32x4 acc = {0.f, 0.f, 0.f, 0.f};
#pragma unroll
        for (int kt = 0; kt < 4; ++kt) {
            s16x8 bfr = *(const s16x8*)(bb + kt * 32);
            acc = __builtin_amdgcn_mfma_f32_16x16x32_bf16(afr[kt], bfr, acc, 0, 0, 0);
        }
        sq0 += acc[0] * acc[0]; sq1 += acc[1] * acc[1];
        sq2 += acc[2] * acc[2]; sq3 += acc[3] * acc[3];
    }
    for (int m = 8; m >= 1; m >>= 1) {
        sq0 += __shfl_xor(sq0, m, 64);
        sq1 += __shfl_xor(sq1, m, 64);
        sq2 += __shfl_xor(sq2, m, 64);
        sq3 += __shfl_xor(sq3, m, 64);
    }
    if (q == 0) {
        sArr[w][g * 4 + 0] = sq0;
        sArr[w][g * 4 + 1] = sq1;
        sArr[w][g * 4 + 2] = sq2;
        sArr[w][g * 4 + 3] = sq3;
    }
    __syncthreads();
    if (t < 16) {
        float v = sArr[0][t] - sArr[1][t] + 1.0f;
        out_hot[i0 + t] = v > 0.f ? v : 0.f;
    } else if (t < 32) {
        int s = t - 16;
        float v = sArr[2][s] - sArr[3][s] + 1.0f;
        out_cold[i0 + s] = v > 0.f ? v : 0.f;
    }

    if (blockIdx.x == 0) {
        red[t] = vae_part[t];
        __syncthreads();
        for (int off = 128; off > 0; off >>= 1) {
            if (t < off) red[t] += red[t + off];
            __syncthreads();
        }
        if (t == 0) out_scalar[0] = red[0];
    }
}

// ---------------------------------------------------------------------------
extern "C" void kernel_launch(void* const* d_in, const int* in_sizes, int n_in,
                              void* d_out, int out_size, void* d_ws, size_t ws_size,
                              hipStream_t stream) {
    const int*   user_idx  = (const int*)d_in[0];
    const int*   user_feat = (const int*)d_in[1];
    const int*   pos_idx   = (const int*)d_in[2];
    const int*   pos_feat  = (const int*)d_in[3];
    const int*   neg_idx   = (const int*)d_in[4];
    const int*   neg_feat  = (const int*)d_in[5];
    const int*   comp_idx  = (const int*)d_in[6];
    const float* eps       = (const float*)d_in[7];
    const float* emb_user  = (const float*)d_in[8];
    const float* emb_item  = (const float*)d_in[9];
    const float* ef_user   = (const float*)d_in[10];
    const float* ef_item   = (const float*)d_in[11];
    const float* pop_u     = (const float*)d_in[12];
    const float* int_u     = (const float*)d_in[13];
    const float* pop_i     = (const float*)d_in[14];
    const float* int_i     = (const float*)d_in[15];
    const float* W_pop     = (const float*)d_in[16];
    const float* W_int     = (const float*)d_in[18];
    const float* enc_W     = (const float*)d_in[20];
    const float* enc_b     = (const float*)d_in[21];
    const float* dec_W     = (const float*)d_in[22];
    const float* dec_b     = (const float*)d_in[23];
    const float* fc11_W    = (const float*)d_in[24];
    const float* fc11_b    = (const float*)d_in[25];
    const float* fc12_W    = (const float*)d_in[26];
    const float* fc12_b    = (const float*)d_in[27];

    float* out = (float*)d_out;
    char*  ws  = (char*)d_ws;

    short* encWT    = (short*)(ws);                    //   655,360 B
    short* decWT    = (short*)(ws + 655360);           //   655,360
    short* fc11WT   = (short*)(ws + 1310720);          //    32,768
    short* fc12WT   = (short*)(ws + 1343488);          //    32,768
    short* wpopT    = (short*)(ws + 1376256);          //    32,768
    short* wintT    = (short*)(ws + 1409024);          //    32,768
    short* ef16     = (short*)(ws + 1441792);          // 1,280,000
    short* efU16    = (short*)(ws + 2721792);          //   512,000
    unsigned short* pooled = (unsigned short*)(ws + 4282368);  // 6,291,456 (bf16)
    float* vae_part = (float*)(ws + 10573824);         //     1,024
    float* projIP   = (float*)(ws + 10574848);         //    20,000
    float* projII   = (float*)(ws + 10594848);         //    20,000
    float* projUP   = (float*)(ws + 10614848);         //     8,000
    float* projUI   = (float*)(ws + 10622848);         //     8,000

    k_prep<<<dim3(2454), dim3(256), 0, stream>>>(
        enc_W, dec_W, fc11_W, fc12_W, W_pop, W_int, ef_item, ef_user,
        pop_i, int_i, pop_u, int_u,
        encWT, decWT, fc11WT, fc12WT, wpopT, wintT, ef16, efU16,
        projIP, projII, projUP, projUI);

    k_AB<<<dim3(1792), dim3(512), 0, stream>>>(
        user_idx, user_feat, pos_idx, pos_feat, neg_idx, neg_feat, comp_idx,
        emb_user, emb_item, ef_item,
        pop_u, int_u, pop_i, int_i,
        eps, enc_b, dec_b, fc11_b, fc12_b,
        encWT, decWT, fc11WT, fc12WT, ef16, efU16,
        projIP, projII, projUP, projUI,
        pooled, vae_part);

    k_loss<<<dim3(256), dim3(256), 0, stream>>>(
        pooled, wpopT, wintT, vae_part,
        out, out + BATCH, out + 2 * BATCH);
}